// Round 19
// baseline (121.514 us; speedup 1.0000x reference)
//
#include <hip/hip_runtime.h>

#define B_ 8
#define C_ 256
#define CI_ 128
#define N_ 4096
#define M_ 1024

typedef unsigned short u16;
typedef unsigned int u32;
typedef _Float16 f16x8 __attribute__((ext_vector_type(8)));
typedef _Float16 f16x4 __attribute__((ext_vector_type(4)));
typedef float f32x4 __attribute__((ext_vector_type(4)));
typedef u16 u16x4 __attribute__((ext_vector_type(4)));
typedef u16 u16x8 __attribute__((ext_vector_type(8)));

__device__ __forceinline__ u16 f2h(float f) {
    _Float16 h = (_Float16)f;
    u16 u;
    __builtin_memcpy(&u, &h, 2);
    return u;
}
__device__ __forceinline__ float h2f(u16 u) {
    _Float16 h;
    __builtin_memcpy(&h, &u, 2);
    return (float)h;
}
__device__ __forceinline__ f16x8 ldh8(const u16* p) {
    return *reinterpret_cast<const f16x8*>(p);
}
__device__ __forceinline__ f16x4 ldh4(const u16* p) {
    return *reinterpret_cast<const f16x4*>(p);
}
__device__ __forceinline__ f32x4 MFMAH(f16x8 a, f16x8 b, f32x4 c) {
    return __builtin_amdgcn_mfma_f32_16x16x32_f16(a, b, c, 0, 0, 0);
}
__device__ __forceinline__ f32x4 MFMA16(f16x4 a, f16x4 b, f32x4 c) {
    return __builtin_amdgcn_mfma_f32_16x16x16f16(a, b, c, 0, 0, 0);
}

// fragment-linear layout: [tile16][ks][lane(64)][8]; value (row-in-16 = lane&15,
// k = ks*32 + (lane>>4)*8 + e). Same layout serves as A-frag (row) or B-frag (col).
// V tile (gpf): K16-frag-linear (see R17), conflict-free mfma16 A-frag reads.

// ---------------- weight prep (fp16) ----------------
__global__ __launch_bounds__(256) void k_prep(
    const float* __restrict__ tw, const float* __restrict__ tb,
    const float* __restrict__ pw, const float* __restrict__ pb,
    const float* __restrict__ gw, const float* __restrict__ gb,
    const float* __restrict__ Ww,
    u16* __restrict__ wcf, float* __restrict__ bcat, u16* __restrict__ wwf) {
    int idx = blockIdx.x * 256 + threadIdx.x;
    if (idx < 384 * 256) {
        int r = idx >> 8, c = idx & 255;
        float v = (r < 128) ? tw[r * 256 + c]
                : (r < 256) ? pw[(r - 128) * 256 + c]
                            : gw[(r - 256) * 256 + c];
        size_t off = (size_t)((r >> 4) * 8 + (c >> 5)) * 512 +
                     (((c >> 3) & 3) * 16 + (r & 15)) * 8 + (c & 7);
        wcf[off] = f2h(v);
    } else if (idx < 384 * 256 + 256 * 128) {
        int k2 = idx - 384 * 256;
        int c = k2 >> 7, k = k2 & 127;
        size_t off = (size_t)((c >> 4) * 4 + (k >> 5)) * 512 +
                     (((k >> 3) & 3) * 16 + (c & 15)) * 8 + (k & 7);
        wwf[off] = f2h(Ww[k2]);
    } else if (idx < 384 * 256 + 256 * 128 + 384) {
        int r = idx - (384 * 256 + 256 * 128);
        bcat[r] = (r < 128) ? tb[r] : (r < 256) ? pb[r - 128] : gb[r - 256];
    }
}

// ---------------- x (B,C,N) fp32 -> fragment-linear fp16 ----------------
__global__ __launch_bounds__(256) void k_tx(const float* __restrict__ x,
                                            u16* __restrict__ xbf) {
    int bid = blockIdx.x;
    int b = bid >> 8, rem = bid & 255, nt = rem >> 2, ct = rem & 3;
    int n0 = nt * 64, c0 = ct * 64;
    __shared__ u16 th_[64][66];
    int j = threadIdx.x & 63, i0 = threadIdx.x >> 6;
    for (int i = i0; i < 64; i += 4)
        th_[i][j] = f2h(x[((size_t)b * C_ + c0 + i) * N_ + n0 + j]);
    __syncthreads();
    int w = threadIdx.x >> 6, lane = threadIdx.x & 63;
    int l15 = lane & 15, g16 = lane >> 4;
    int s = w;
#pragma unroll
    for (int kk = 0; kk < 2; ++kk) {
        u16x8 hv;
#pragma unroll
        for (int e = 0; e < 8; ++e)
            hv[e] = th_[kk * 32 + g16 * 8 + e][s * 16 + l15];
        size_t off = ((size_t)(b * 256 + (n0 >> 4) + s) * 8 + (c0 >> 5) + kk) * 512 +
                     (size_t)lane * 8;
        *(u16x8*)&xbf[off] = hv;
    }
}

// ---------------- projection GEMM (fp16) + fused 2x2 pooling epilogue ----------------
__global__ __launch_bounds__(256) void k_proj(
    const u16* __restrict__ wcf, const float* __restrict__ bcat,
    const u16* __restrict__ xbf,
    u16* __restrict__ thf, u16* __restrict__ ppf, u16* __restrict__ gpf) {
    int bid = blockIdx.x;
    int b = bid / 96, rem = bid % 96, rt = rem >> 5, nt = rem & 31;
    int tid = threadIdx.x;
    int w = tid >> 6, lane = tid & 63;
    int l15 = lane & 15, g16 = lane >> 4;
    int wr = (w >> 1) * 64, wc = (w & 1) * 64;
    int rbase = rt * 128 + wr, nbase = nt * 128 + wc;
    __shared__ u16 tl[128][132];
    f32x4 acc[4][4];
#pragma unroll
    for (int i = 0; i < 4; ++i)
#pragma unroll
        for (int j = 0; j < 4; ++j)
#pragma unroll
            for (int r = 0; r < 4; ++r) acc[i][j][r] = 0.f;
#pragma unroll
    for (int ks = 0; ks < 8; ++ks) {
        f16x8 a[4], bb[4];
#pragma unroll
        for (int i = 0; i < 4; ++i)
            a[i] = ldh8(&wcf[((size_t)((rbase >> 4) + i) * 8 + ks) * 512 + (size_t)lane * 8]);
#pragma unroll
        for (int j = 0; j < 4; ++j)
            bb[j] = ldh8(&xbf[((size_t)(b * 256 + (nbase >> 4) + j) * 8 + ks) * 512 +
                              (size_t)lane * 8]);
#pragma unroll
        for (int i = 0; i < 4; ++i)
#pragma unroll
            for (int j = 0; j < 4; ++j) acc[i][j] = MFMAH(a[i], bb[j], acc[i][j]);
    }
    if (rt == 0) {
#pragma unroll
        for (int i = 0; i < 4; ++i) {
            int lrow = wr + i * 16 + g16 * 4;
#pragma unroll
            for (int j = 0; j < 4; ++j) {
                u16x4 pk;
#pragma unroll
                for (int r = 0; r < 4; ++r)
                    pk[r] = f2h(acc[i][j][r] + bcat[lrow + r]);
                size_t off = ((size_t)(b * 256 + (nbase >> 4) + j) * 4 + (lrow >> 5)) * 512 +
                             (((lrow >> 3) & 3) * 16 + l15) * 8 + (lrow & 7);
                *reinterpret_cast<u16x4*>(&thf[off]) = pk;
            }
        }
    } else {
#pragma unroll
        for (int i = 0; i < 4; ++i) {
            int lrow = wr + i * 16 + g16 * 4;
#pragma unroll
            for (int j = 0; j < 4; ++j) {
                int n_loc = wc + j * 16 + l15;
                u16x4 pk;
#pragma unroll
                for (int r = 0; r < 4; ++r)
                    pk[r] = f2h(acc[i][j][r] + bcat[rt * 128 + lrow + r]);
                *reinterpret_cast<u16x4*>(&tl[n_loc][lrow]) = pk;
            }
        }
        __syncthreads();
        if (rt == 1) {
#pragma unroll
            for (int half = 0; half < 2; ++half) {
                int w2 = (tid >> 4) + half * 16;
                int c8 = tid & 15;
                u16x8 v0 = *(const u16x8*)&tl[2 * w2][c8 * 8];
                u16x8 v1 = *(const u16x8*)&tl[2 * w2 + 1][c8 * 8];
                u16x8 v2 = *(const u16x8*)&tl[64 + 2 * w2][c8 * 8];
                u16x8 v3 = *(const u16x8*)&tl[65 + 2 * w2][c8 * 8];
                u16x8 o;
#pragma unroll
                for (int e = 0; e < 8; ++e) {
                    float mx = fmaxf(fmaxf(h2f(v0[e]), h2f(v1[e])),
                                     fmaxf(h2f(v2[e]), h2f(v3[e])));
                    o[e] = f2h(mx);
                }
                size_t off = ((size_t)(((b * 32 + nt) * 2 + (w2 >> 4)) * 4 + (c8 >> 2)) * 64 +
                              (c8 & 3) * 16 + (w2 & 15)) * 8;
                *(u16x8*)&ppf[off] = o;
            }
        } else {
            // g pooled -> gpf K16-frag-linear (conflict-free mfma16 A-frag reads)
#pragma unroll
            for (int s = 0; s < 2; ++s) {
                int wg = (tid >> 7) + s * 2;
                int ci = tid & 127;
                u16x4 o0, o1;
#pragma unroll
                for (int e = 0; e < 4; ++e) {
                    int w2a = wg * 8 + e;
                    int w2b = wg * 8 + 4 + e;
                    float va = fmaxf(fmaxf(h2f(tl[2 * w2a][ci]), h2f(tl[2 * w2a + 1][ci])),
                                     fmaxf(h2f(tl[64 + 2 * w2a][ci]), h2f(tl[65 + 2 * w2a][ci])));
                    float vb = fmaxf(fmaxf(h2f(tl[2 * w2b][ci]), h2f(tl[2 * w2b + 1][ci])),
                                     fmaxf(h2f(tl[64 + 2 * w2b][ci]), h2f(tl[65 + 2 * w2b][ci])));
                    o0[e] = f2h(va);
                    o1[e] = f2h(vb);
                }
                size_t base = (size_t)(b * 32 + nt) * 4096 +
                              (size_t)(((wg >> 1) * 8) + (ci >> 4)) * 256 + (ci & 15) * 4;
                *(u16x4*)&gpf[base + (((wg * 2) & 3) * 64)] = o0;
                *(u16x4*)&gpf[base + (((wg * 2 + 1) & 3) * 64)] = o1;
            }
        }
    }
}

// ---------------- flash attention (split-m=2, BARRIER-FREE, L2-direct loads) ----
// No LDS at all: each wave reads K/V fragments straight from L2 (XCD-swizzled
// working set is L2-resident). Waves free-run; compiler pipelines loads across
// iterations with no sync points.
__global__ __launch_bounds__(256) void k_attn(
    const u16* __restrict__ thf, const u16* __restrict__ ppf,
    const u16* __restrict__ gpf,
    u16* __restrict__ of, float2* __restrict__ ml) {
    int bid = blockIdx.x;
    int b = bid & 7, r = bid >> 3;   // same-b blocks -> same XCD (L2 locality)
    int sp = r >> 6, nt = r & 63;    // sp in 0..1
    int tid = threadIdx.x;
    int w = tid >> 6, lane = tid & 63;
    int l15 = lane & 15, g16 = lane >> 4;
    int n = nt * 64 + w * 16 + l15;
    int t16 = nt * 4 + w;

    f16x8 qf[4];
#pragma unroll
    for (int ks = 0; ks < 4; ++ks)
        qf[ks] = ldh8(&thf[((size_t)(b * 256 + t16) * 4 + ks) * 512 + (size_t)lane * 8]);

    f32x4 o[8];
#pragma unroll
    for (int ct = 0; ct < 8; ++ct)
#pragma unroll
        for (int rr = 0; rr < 4; ++rr) o[ct][rr] = 0.f;
    float mrun = -1e30f, lpart = 0.f;

    int itg0 = sp * 16;
    for (int it = 0; it < 16; ++it) {
        const u16* pt = &ppf[(size_t)(b * 32 + itg0 + it) * 4096];
        const u16* gt = &gpf[(size_t)(b * 32 + itg0 + it) * 4096];
        // (B) QK^T: K frags direct from L2
        f32x4 s0 = {0.f, 0.f, 0.f, 0.f}, s1 = {0.f, 0.f, 0.f, 0.f};
#pragma unroll
        for (int ks = 0; ks < 4; ++ks) {
            f16x8 pa0 = ldh8(&pt[ks * 512 + lane * 8]);
            f16x8 pa1 = ldh8(&pt[(4 + ks) * 512 + lane * 8]);
            s0 = MFMAH(pa0, qf[ks], s0);
            s1 = MFMAH(pa1, qf[ks], s1);
        }
        // lane-local max; ballot-gated lazy rescale (P bounded by e^8, fp16-safe)
        float pm8 = s0[0];
#pragma unroll
        for (int rr = 1; rr < 4; ++rr) pm8 = fmaxf(pm8, s0[rr]);
#pragma unroll
        for (int rr = 0; rr < 4; ++rr) pm8 = fmaxf(pm8, s1[rr]);
        if (__any(pm8 > mrun + 8.0f)) {
            float pm = fmaxf(pm8, __shfl_xor(pm8, 16));
            pm = fmaxf(pm, __shfl_xor(pm, 32));
            float mnew = fmaxf(mrun, pm);
            float sc = __expf(mrun - mnew);
#pragma unroll
            for (int ct = 0; ct < 8; ++ct)
#pragma unroll
                for (int rr = 0; rr < 4; ++rr) o[ct][rr] *= sc;
            lpart *= sc;
            mrun = mnew;
        }
        // P stays in registers: pack directly into the two 16x16x16 B-frags.
        f16x4 pb0, pb1;
#pragma unroll
        for (int rr = 0; rr < 4; ++rr) {
            float p0 = __expf(s0[rr] - mrun);
            float p1 = __expf(s1[rr] - mrun);
            lpart += p0 + p1;
            pb0[rr] = (_Float16)p0;
            pb1[rr] = (_Float16)p1;
        }
        // (C) PV: V frags direct from L2 (K16-frag-linear, coalesced 8B/lane)
#pragma unroll
        for (int ct = 0; ct < 8; ++ct) {
            f16x4 g0 = ldh4(&gt[ct * 256 + lane * 4]);
            f16x4 g1 = ldh4(&gt[2048 + ct * 256 + lane * 4]);
            o[ct] = MFMA16(g0, pb0, o[ct]);
            o[ct] = MFMA16(g1, pb1, o[ct]);
        }
    }
    // column l-sum: single reduce after the loop
    float lcol = lpart + __shfl_xor(lpart, 16);
    lcol += __shfl_xor(lcol, 32);
    float linv = 1.f / lcol;
    size_t obase = ((size_t)(b * 2 + sp) * N_ + n) * CI_;
#pragma unroll
    for (int ct = 0; ct < 8; ++ct) {
        u16x4 pk;
#pragma unroll
        for (int rr = 0; rr < 4; ++rr) pk[rr] = f2h(o[ct][rr] * linv);
        *reinterpret_cast<u16x4*>(&of[obase + ct * 16 + g16 * 4]) = pk;
    }
    if (g16 == 0) ml[(size_t)(b * 2 + sp) * N_ + n] = make_float2(mrun, lcol);
}

// ---------------- W conv GEMM (fused 2-split combine + fp16 GEMM) ----------------
__global__ __launch_bounds__(256) void k_wconv(
    const u16* __restrict__ wwf, const float* __restrict__ Wb,
    const u16* __restrict__ of, const float2* __restrict__ ml,
    u16* __restrict__ z) {
    int bid = blockIdx.x;
    int b = bid >> 6, rem = bid & 63, ct2 = rem >> 5, nt = rem & 31;
    int w = threadIdx.x >> 6, lane = threadIdx.x & 63;
    int l15 = lane & 15, g16 = lane >> 4;
    int nbase = nt * 128 + (w >> 1) * 64;
    int cbase = ct2 * 128 + (w & 1) * 64;
    const size_t spstride = (size_t)N_ * CI_;
    float wsp[4][2];
#pragma unroll
    for (int i = 0; i < 4; ++i) {
        int n = nbase + i * 16 + l15;
        float2 m0 = ml[(size_t)(b * 2 + 0) * N_ + n];
        float2 m1 = ml[(size_t)(b * 2 + 1) * N_ + n];
        float M = fmaxf(m0.x, m1.x);
        float w0 = __expf(m0.x - M) * m0.y;
        float w1 = __expf(m1.x - M) * m1.y;
        float invL = 1.f / (w0 + w1);
        wsp[i][0] = w0 * invL;
        wsp[i][1] = w1 * invL;
    }
    f32x4 acc[4][4];
#pragma unroll
    for (int i = 0; i < 4; ++i)
#pragma unroll
        for (int j = 0; j < 4; ++j)
#pragma unroll
            for (int r = 0; r < 4; ++r) acc[i][j][r] = 0.f;
#pragma unroll
    for (int ks = 0; ks < 4; ++ks) {
        f16x8 a[4], bb[4];
#pragma unroll
        for (int i = 0; i < 4; ++i) {
            int n = nbase + i * 16 + l15;
            size_t base = ((size_t)(b * 2) * N_ + n) * CI_ + ks * 32 + g16 * 8;
            u16x8 v0 = *(const u16x8*)&of[base];
            u16x8 v1 = *(const u16x8*)&of[base + spstride];
            f16x8 av;
#pragma unroll
            for (int e = 0; e < 8; ++e) {
                float vv = h2f(v0[e]) * wsp[i][0] + h2f(v1[e]) * wsp[i][1];
                av[e] = (_Float16)vv;
            }
            a[i] = av;
        }
#pragma unroll
        for (int j = 0; j < 4; ++j)
            bb[j] = ldh8(&wwf[((size_t)((cbase >> 4) + j) * 4 + ks) * 512 + (size_t)lane * 8]);
#pragma unroll
        for (int i = 0; i < 4; ++i)
#pragma unroll
            for (int j = 0; j < 4; ++j) acc[i][j] = MFMAH(a[i], bb[j], acc[i][j]);
    }
#pragma unroll
    for (int j = 0; j < 4; ++j) {
        int ch = cbase + j * 16 + l15;
        float bias = Wb[ch];
        size_t rowbase = ((size_t)b * C_ + ch) * N_;
#pragma unroll
        for (int i = 0; i < 4; ++i) {
            u16x4 pk;
#pragma unroll
            for (int r = 0; r < 4; ++r) pk[r] = f2h(acc[i][j][r] + bias);
            *reinterpret_cast<u16x4*>(&z[rowbase + nbase + i * 16 + g16 * 4]) = pk;
        }
    }
}

// ---------------- BN stats + finalize ----------------
__global__ __launch_bounds__(256) void k_stats(
    const u16* __restrict__ z, const float* __restrict__ gamma,
    const float* __restrict__ beta, float* __restrict__ bnp) {
    int c = blockIdx.x;
    int tid = threadIdx.x;
    float s = 0.f, q = 0.f;
#pragma unroll
    for (int b = 0; b < B_; ++b) {
        size_t base = ((size_t)b * C_ + c) * N_ + tid * 16;
        u16x8 v0 = *(const u16x8*)&z[base];
        u16x8 v1 = *(const u16x8*)&z[base + 8];
#pragma unroll
        for (int e = 0; e < 8; ++e) {
            float v = h2f(v0[e]);
            s += v;
            q += v * v;
            float u = h2f(v1[e]);
            s += u;
            q += u * u;
        }
    }
#pragma unroll
    for (int off = 1; off <= 32; off <<= 1) {
        s += __shfl_xor(s, off);
        q += __shfl_xor(q, off);
    }
    __shared__ float ss[4], qq[4];
    int w = tid >> 6;
    if ((tid & 63) == 0) {
        ss[w] = s;
        qq[w] = q;
    }
    __syncthreads();
    if (tid == 0) {
        s = ss[0] + ss[1] + ss[2] + ss[3];
        q = qq[0] + qq[1] + qq[2] + qq[3];
        const float inv_n = 1.f / 32768.f;
        float mean = s * inv_n;
        float var = q * inv_n - mean * mean;
        float sc = gamma[c] * rsqrtf(var + 1e-5f);
        bnp[c] = sc;
        bnp[256 + c] = beta[c] - mean * sc;
    }
}

// ---------------- apply BN + residual ----------------
__global__ __launch_bounds__(256) void k_final(
    const float* __restrict__ x, const u16* __restrict__ z,
    const float* __restrict__ bnp, float* __restrict__ out) {
    int i4 = blockIdx.x * 256 + threadIdx.x;
    size_t flat = (size_t)i4 * 4;
    int c = (int)((flat >> 12) & 255);
    float sc = bnp[c], sh = bnp[256 + c];
    float4 xx = *(const float4*)&x[flat];
    u16x4 zz = *(const u16x4*)&z[flat];
    float4 oo;
    oo.x = xx.x + h2f(zz[0]) * sc + sh;
    oo.y = xx.y + h2f(zz[1]) * sc + sh;
    oo.z = xx.z + h2f(zz[2]) * sc + sh;
    oo.w = xx.w + h2f(zz[3]) * sc + sh;
    *(float4*)&out[flat] = oo;
}

extern "C" void kernel_launch(void* const* d_in, const int* in_sizes, int n_in,
                              void* d_out, int out_size, void* d_ws, size_t ws_size,
                              hipStream_t stream) {
    const float* x     = (const float*)d_in[0];
    const float* tw    = (const float*)d_in[1];
    const float* tb    = (const float*)d_in[2];
    const float* pw    = (const float*)d_in[3];
    const float* pb    = (const float*)d_in[4];
    const float* gw    = (const float*)d_in[5];
    const float* gb    = (const float*)d_in[6];
    const float* Ww    = (const float*)d_in[7];
    const float* Wb    = (const float*)d_in[8];
    const float* gamma = (const float*)d_in[9];
    const float* beta  = (const float*)d_in[10];
    float* out = (float*)d_out;

    char* p = (char*)d_ws;
    auto alloc = [&](size_t bytes) {
        char* r = p;
        p += (bytes + 255) & ~(size_t)255;
        return r;
    };
    u16* xbf   = (u16*)alloc((size_t)B_ * N_ * C_ * 2);          // 16.8 MB
    u16* thf   = (u16*)alloc((size_t)B_ * N_ * CI_ * 2);         // 8.4 MB
    u16* ppf   = (u16*)alloc((size_t)B_ * M_ * CI_ * 2);         // 2.1 MB
    u16* gpf   = (u16*)alloc((size_t)B_ * M_ * CI_ * 2);         // 2.1 MB
    float2* ml = (float2*)alloc((size_t)2 * B_ * N_ * 8);        // 512 KB
    u16* of    = (u16*)alloc((size_t)2 * B_ * N_ * CI_ * 2);     // 16.8 MB
    u16* z     = (u16*)alloc((size_t)B_ * C_ * N_ * 2);          // 16.8 MB
    u16* wcf   = (u16*)alloc(384 * 256 * 2);
    u16* wwf   = (u16*)alloc(256 * 128 * 2);
    float* bcat = (float*)alloc(384 * 4);
    float* bnp  = (float*)alloc(512 * 4);

    k_prep<<<514, 256, 0, stream>>>(tw, tb, pw, pb, gw, gb, Ww, wcf, bcat, wwf);
    k_tx<<<2048, 256, 0, stream>>>(x, xbf);
    k_proj<<<768, 256, 0, stream>>>(wcf, bcat, xbf, thf, ppf, gpf);
    k_attn<<<1024, 256, 0, stream>>>(thf, ppf, gpf, of, ml);
    k_wconv<<<512, 256, 0, stream>>>(wwf, Wb, of, ml, z);
    k_stats<<<256, 256, 0, stream>>>(z, gamma, beta, bnp);
    k_final<<<8192, 256, 0, stream>>>(x, z, bnp, out);
}

// Round 20
// 103.626 us; speedup vs baseline: 1.1726x; 1.1726x over previous
//
#include <hip/hip_runtime.h>

#define B_ 8
#define C_ 256
#define CI_ 128
#define N_ 4096
#define M_ 1024

typedef unsigned short u16;
typedef unsigned int u32;
typedef _Float16 f16x8 __attribute__((ext_vector_type(8)));
typedef _Float16 f16x4 __attribute__((ext_vector_type(4)));
typedef float f32x4 __attribute__((ext_vector_type(4)));
typedef u16 u16x4 __attribute__((ext_vector_type(4)));
typedef u16 u16x8 __attribute__((ext_vector_type(8)));

__device__ __forceinline__ u16 f2h(float f) {
    _Float16 h = (_Float16)f;
    u16 u;
    __builtin_memcpy(&u, &h, 2);
    return u;
}
__device__ __forceinline__ float h2f(u16 u) {
    _Float16 h;
    __builtin_memcpy(&h, &u, 2);
    return (float)h;
}
__device__ __forceinline__ f16x8 ldh8(const u16* p) {
    return *reinterpret_cast<const f16x8*>(p);
}
__device__ __forceinline__ f32x4 MFMAH(f16x8 a, f16x8 b, f32x4 c) {
    return __builtin_amdgcn_mfma_f32_16x16x32_f16(a, b, c, 0, 0, 0);
}
__device__ __forceinline__ f32x4 MFMA16(f16x4 a, f16x4 b, f32x4 c) {
    return __builtin_amdgcn_mfma_f32_16x16x16f16(a, b, c, 0, 0, 0);
}
// async global->LDS: lds dst is wave-uniform base, HW adds lane*16B; src per-lane
__device__ __forceinline__ void gld16(const u16* g, u16* l) {
    __builtin_amdgcn_global_load_lds(
        (const __attribute__((address_space(1))) void*)g,
        (__attribute__((address_space(3))) void*)l, 16, 0, 0);
}

// fragment-linear layout: [tile16][ks][lane(64)][8]; value (row-in-16 = lane&15,
// k = ks*32 + (lane>>4)*8 + e). Same layout serves as A-frag (row) or B-frag (col).
// V tile (gpf): K16-frag-linear (see R17), conflict-free mfma16 A-frag reads.

// ---------------- weight prep (fp16) ----------------
__global__ __launch_bounds__(256) void k_prep(
    const float* __restrict__ tw, const float* __restrict__ tb,
    const float* __restrict__ pw, const float* __restrict__ pb,
    const float* __restrict__ gw, const float* __restrict__ gb,
    const float* __restrict__ Ww,
    u16* __restrict__ wcf, float* __restrict__ bcat, u16* __restrict__ wwf) {
    int idx = blockIdx.x * 256 + threadIdx.x;
    if (idx < 384 * 256) {
        int r = idx >> 8, c = idx & 255;
        float v = (r < 128) ? tw[r * 256 + c]
                : (r < 256) ? pw[(r - 128) * 256 + c]
                            : gw[(r - 256) * 256 + c];
        size_t off = (size_t)((r >> 4) * 8 + (c >> 5)) * 512 +
                     (((c >> 3) & 3) * 16 + (r & 15)) * 8 + (c & 7);
        wcf[off] = f2h(v);
    } else if (idx < 384 * 256 + 256 * 128) {
        int k2 = idx - 384 * 256;
        int c = k2 >> 7, k = k2 & 127;
        size_t off = (size_t)((c >> 4) * 4 + (k >> 5)) * 512 +
                     (((k >> 3) & 3) * 16 + (c & 15)) * 8 + (k & 7);
        wwf[off] = f2h(Ww[k2]);
    } else if (idx < 384 * 256 + 256 * 128 + 384) {
        int r = idx - (384 * 256 + 256 * 128);
        bcat[r] = (r < 128) ? tb[r] : (r < 256) ? pb[r - 128] : gb[r - 256];
    }
}

// ---------------- x (B,C,N) fp32 -> fragment-linear fp16 ----------------
__global__ __launch_bounds__(256) void k_tx(const float* __restrict__ x,
                                            u16* __restrict__ xbf) {
    int bid = blockIdx.x;
    int b = bid >> 8, rem = bid & 255, nt = rem >> 2, ct = rem & 3;
    int n0 = nt * 64, c0 = ct * 64;
    __shared__ u16 th_[64][66];
    int j = threadIdx.x & 63, i0 = threadIdx.x >> 6;
    for (int i = i0; i < 64; i += 4)
        th_[i][j] = f2h(x[((size_t)b * C_ + c0 + i) * N_ + n0 + j]);
    __syncthreads();
    int w = threadIdx.x >> 6, lane = threadIdx.x & 63;
    int l15 = lane & 15, g16 = lane >> 4;
    int s = w;
#pragma unroll
    for (int kk = 0; kk < 2; ++kk) {
        u16x8 hv;
#pragma unroll
        for (int e = 0; e < 8; ++e)
            hv[e] = th_[kk * 32 + g16 * 8 + e][s * 16 + l15];
        size_t off = ((size_t)(b * 256 + (n0 >> 4) + s) * 8 + (c0 >> 5) + kk) * 512 +
                     (size_t)lane * 8;
        *(u16x8*)&xbf[off] = hv;
    }
}

// ---------------- projection GEMM (fp16) + fused 2x2 pooling epilogue ----------------
__global__ __launch_bounds__(256) void k_proj(
    const u16* __restrict__ wcf, const float* __restrict__ bcat,
    const u16* __restrict__ xbf,
    u16* __restrict__ thf, u16* __restrict__ ppf, u16* __restrict__ gpf) {
    int bid = blockIdx.x;
    int b = bid / 96, rem = bid % 96, rt = rem >> 5, nt = rem & 31;
    int tid = threadIdx.x;
    int w = tid >> 6, lane = tid & 63;
    int l15 = lane & 15, g16 = lane >> 4;
    int wr = (w >> 1) * 64, wc = (w & 1) * 64;
    int rbase = rt * 128 + wr, nbase = nt * 128 + wc;
    __shared__ u16 tl[128][132];
    f32x4 acc[4][4];
#pragma unroll
    for (int i = 0; i < 4; ++i)
#pragma unroll
        for (int j = 0; j < 4; ++j)
#pragma unroll
            for (int r = 0; r < 4; ++r) acc[i][j][r] = 0.f;
#pragma unroll
    for (int ks = 0; ks < 8; ++ks) {
        f16x8 a[4], bb[4];
#pragma unroll
        for (int i = 0; i < 4; ++i)
            a[i] = ldh8(&wcf[((size_t)((rbase >> 4) + i) * 8 + ks) * 512 + (size_t)lane * 8]);
#pragma unroll
        for (int j = 0; j < 4; ++j)
            bb[j] = ldh8(&xbf[((size_t)(b * 256 + (nbase >> 4) + j) * 8 + ks) * 512 +
                              (size_t)lane * 8]);
#pragma unroll
        for (int i = 0; i < 4; ++i)
#pragma unroll
            for (int j = 0; j < 4; ++j) acc[i][j] = MFMAH(a[i], bb[j], acc[i][j]);
    }
    if (rt == 0) {
#pragma unroll
        for (int i = 0; i < 4; ++i) {
            int lrow = wr + i * 16 + g16 * 4;
#pragma unroll
            for (int j = 0; j < 4; ++j) {
                u16x4 pk;
#pragma unroll
                for (int r = 0; r < 4; ++r)
                    pk[r] = f2h(acc[i][j][r] + bcat[lrow + r]);
                size_t off = ((size_t)(b * 256 + (nbase >> 4) + j) * 4 + (lrow >> 5)) * 512 +
                             (((lrow >> 3) & 3) * 16 + l15) * 8 + (lrow & 7);
                *reinterpret_cast<u16x4*>(&thf[off]) = pk;
            }
        }
    } else {
#pragma unroll
        for (int i = 0; i < 4; ++i) {
            int lrow = wr + i * 16 + g16 * 4;
#pragma unroll
            for (int j = 0; j < 4; ++j) {
                int n_loc = wc + j * 16 + l15;
                u16x4 pk;
#pragma unroll
                for (int r = 0; r < 4; ++r)
                    pk[r] = f2h(acc[i][j][r] + bcat[rt * 128 + lrow + r]);
                *reinterpret_cast<u16x4*>(&tl[n_loc][lrow]) = pk;
            }
        }
        __syncthreads();
        if (rt == 1) {
#pragma unroll
            for (int half = 0; half < 2; ++half) {
                int w2 = (tid >> 4) + half * 16;
                int c8 = tid & 15;
                u16x8 v0 = *(const u16x8*)&tl[2 * w2][c8 * 8];
                u16x8 v1 = *(const u16x8*)&tl[2 * w2 + 1][c8 * 8];
                u16x8 v2 = *(const u16x8*)&tl[64 + 2 * w2][c8 * 8];
                u16x8 v3 = *(const u16x8*)&tl[65 + 2 * w2][c8 * 8];
                u16x8 o;
#pragma unroll
                for (int e = 0; e < 8; ++e) {
                    float mx = fmaxf(fmaxf(h2f(v0[e]), h2f(v1[e])),
                                     fmaxf(h2f(v2[e]), h2f(v3[e])));
                    o[e] = f2h(mx);
                }
                size_t off = ((size_t)(((b * 32 + nt) * 2 + (w2 >> 4)) * 4 + (c8 >> 2)) * 64 +
                              (c8 & 3) * 16 + (w2 & 15)) * 8;
                *(u16x8*)&ppf[off] = o;
            }
        } else {
            // g pooled -> gpf K16-frag-linear (conflict-free mfma16 A-frag reads)
#pragma unroll
            for (int s = 0; s < 2; ++s) {
                int wg = (tid >> 7) + s * 2;
                int ci = tid & 127;
                u16x4 o0, o1;
#pragma unroll
                for (int e = 0; e < 4; ++e) {
                    int w2a = wg * 8 + e;
                    int w2b = wg * 8 + 4 + e;
                    float va = fmaxf(fmaxf(h2f(tl[2 * w2a][ci]), h2f(tl[2 * w2a + 1][ci])),
                                     fmaxf(h2f(tl[64 + 2 * w2a][ci]), h2f(tl[65 + 2 * w2a][ci])));
                    float vb = fmaxf(fmaxf(h2f(tl[2 * w2b][ci]), h2f(tl[2 * w2b + 1][ci])),
                                     fmaxf(h2f(tl[64 + 2 * w2b][ci]), h2f(tl[65 + 2 * w2b][ci])));
                    o0[e] = f2h(va);
                    o1[e] = f2h(vb);
                }
                size_t base = (size_t)(b * 32 + nt) * 4096 +
                              (size_t)(((wg >> 1) * 8) + (ci >> 4)) * 256 + (ci & 15) * 4;
                *(u16x4*)&gpf[base + (((wg * 2) & 3) * 64)] = o0;
                *(u16x4*)&gpf[base + (((wg * 2 + 1) & 3) * 64)] = o1;
            }
        }
    }
}

// ---------------- flash attention (split-m=2, async LDS staging, P in-register) ----
__global__ __launch_bounds__(256) void k_attn(
    const u16* __restrict__ thf, const u16* __restrict__ ppf,
    const u16* __restrict__ gpf,
    u16* __restrict__ of, float2* __restrict__ ml) {
    int bid = blockIdx.x;
    int b = bid & 7, r = bid >> 3;   // same-b blocks -> same XCD (L2 locality)
    int sp = r >> 6, nt = r & 63;    // sp in 0..1
    int tid = threadIdx.x;
    int w = tid >> 6, lane = tid & 63;
    int l15 = lane & 15, g16 = lane >> 4;
    int n = nt * 64 + w * 16 + l15;
    int t16 = nt * 4 + w;
    __shared__ u16 kv[2][8192];  // [buf][0..4096): K-tile, [4096..8192): V-tile

    f16x8 qf[4];
#pragma unroll
    for (int ks = 0; ks < 4; ++ks)
        qf[ks] = ldh8(&thf[((size_t)(b * 256 + t16) * 4 + ks) * 512 + (size_t)lane * 8]);

    f32x4 o[8];
#pragma unroll
    for (int ct = 0; ct < 8; ++ct)
#pragma unroll
        for (int rr = 0; rr < 4; ++rr) o[ct][rr] = 0.f;
    float mrun = -1e30f, lpart = 0.f;

    int itg0 = sp * 16;
    int soff = w * 512 + lane * 8;  // per-lane src offset (u16)
    // async stage of tile itg into kv[bufidx] (wave-linear dest, 4 x 1KB/wave)
    auto stage = [&](int bufidx, int itg) {
        const u16* ps = &ppf[(size_t)(b * 32 + itg) * 4096];
        const u16* gs = &gpf[(size_t)(b * 32 + itg) * 4096];
        u16* kb = &kv[bufidx][w * 512];
        gld16(ps + soff, kb);
        gld16(ps + 2048 + soff, kb + 2048);
        gld16(gs + soff, kb + 4096);
        gld16(gs + 2048 + soff, kb + 6144);
    };
    stage(0, itg0);
    __syncthreads();  // drains vmcnt -> tile 0 visible
    int cur = 0;

    for (int it = 0; it < 16; ++it) {
        // (A) issue next tile's async loads (land by end-of-iter barrier)
        if (it < 15) stage(cur ^ 1, itg0 + it + 1);
        // (B) QK^T from kv[cur]
        f32x4 s0 = {0.f, 0.f, 0.f, 0.f}, s1 = {0.f, 0.f, 0.f, 0.f};
        __builtin_amdgcn_s_setprio(1);
#pragma unroll
        for (int ks = 0; ks < 4; ++ks) {
            f16x8 pa0 = ldh8(&kv[cur][ks * 512 + lane * 8]);
            f16x8 pa1 = ldh8(&kv[cur][(4 + ks) * 512 + lane * 8]);
            s0 = MFMAH(pa0, qf[ks], s0);
            s1 = MFMAH(pa1, qf[ks], s1);
        }
        __builtin_amdgcn_s_setprio(0);
        // lane-local max; ballot-gated lazy rescale (P bounded by e^8, fp16-safe)
        float pm8 = s0[0];
#pragma unroll
        for (int rr = 1; rr < 4; ++rr) pm8 = fmaxf(pm8, s0[rr]);
#pragma unroll
        for (int rr = 0; rr < 4; ++rr) pm8 = fmaxf(pm8, s1[rr]);
        if (__any(pm8 > mrun + 8.0f)) {
            float pm = fmaxf(pm8, __shfl_xor(pm8, 16));
            pm = fmaxf(pm, __shfl_xor(pm, 32));
            float mnew = fmaxf(mrun, pm);
            float sc = __expf(mrun - mnew);
#pragma unroll
            for (int ct = 0; ct < 8; ++ct)
#pragma unroll
                for (int rr = 0; rr < 4; ++rr) o[ct][rr] *= sc;
            lpart *= sc;
            mrun = mnew;
        }
        // P stays in registers: pack directly into the two 16x16x16 B-frags.
        f16x4 pb0, pb1;
#pragma unroll
        for (int rr = 0; rr < 4; ++rr) {
            float p0 = __expf(s0[rr] - mrun);
            float p1 = __expf(s1[rr] - mrun);
            lpart += p0 + p1;
            pb0[rr] = (_Float16)p0;
            pb1[rr] = (_Float16)p1;
        }
        // (C) PV from kv[cur] V-tile (K16-frag-linear): conflict-free 8B reads
        __builtin_amdgcn_s_setprio(1);
#pragma unroll
        for (int ct = 0; ct < 8; ++ct) {
            f16x4 g0 = *reinterpret_cast<const f16x4*>(&kv[cur][4096 + ct * 256 + lane * 4]);
            f16x4 g1 = *reinterpret_cast<const f16x4*>(&kv[cur][6144 + ct * 256 + lane * 4]);
            o[ct] = MFMA16(g0, pb0, o[ct]);
            o[ct] = MFMA16(g1, pb1, o[ct]);
        }
        __builtin_amdgcn_s_setprio(0);
        __syncthreads();  // drains vmcnt (next tile staged) + all kv[cur] reads done
        cur ^= 1;
    }
    // column l-sum: single reduce after the loop
    float lcol = lpart + __shfl_xor(lpart, 16);
    lcol += __shfl_xor(lcol, 32);
    float linv = 1.f / lcol;
    size_t obase = ((size_t)(b * 2 + sp) * N_ + n) * CI_;
#pragma unroll
    for (int ct = 0; ct < 8; ++ct) {
        u16x4 pk;
#pragma unroll
        for (int rr = 0; rr < 4; ++rr) pk[rr] = f2h(o[ct][rr] * linv);
        *reinterpret_cast<u16x4*>(&of[obase + ct * 16 + g16 * 4]) = pk;
    }
    if (g16 == 0) ml[(size_t)(b * 2 + sp) * N_ + n] = make_float2(mrun, lcol);
}

// ---------------- W conv GEMM (fused 2-split combine + fp16 GEMM) ----------------
__global__ __launch_bounds__(256) void k_wconv(
    const u16* __restrict__ wwf, const float* __restrict__ Wb,
    const u16* __restrict__ of, const float2* __restrict__ ml,
    u16* __restrict__ z) {
    int bid = blockIdx.x;
    int b = bid >> 6, rem = bid & 63, ct2 = rem >> 5, nt = rem & 31;
    int w = threadIdx.x >> 6, lane = threadIdx.x & 63;
    int l15 = lane & 15, g16 = lane >> 4;
    int nbase = nt * 128 + (w >> 1) * 64;
    int cbase = ct2 * 128 + (w & 1) * 64;
    const size_t spstride = (size_t)N_ * CI_;
    float wsp[4][2];
#pragma unroll
    for (int i = 0; i < 4; ++i) {
        int n = nbase + i * 16 + l15;
        float2 m0 = ml[(size_t)(b * 2 + 0) * N_ + n];
        float2 m1 = ml[(size_t)(b * 2 + 1) * N_ + n];
        float M = fmaxf(m0.x, m1.x);
        float w0 = __expf(m0.x - M) * m0.y;
        float w1 = __expf(m1.x - M) * m1.y;
        float invL = 1.f / (w0 + w1);
        wsp[i][0] = w0 * invL;
        wsp[i][1] = w1 * invL;
    }
    f32x4 acc[4][4];
#pragma unroll
    for (int i = 0; i < 4; ++i)
#pragma unroll
        for (int j = 0; j < 4; ++j)
#pragma unroll
            for (int r = 0; r < 4; ++r) acc[i][j][r] = 0.f;
#pragma unroll
    for (int ks = 0; ks < 4; ++ks) {
        f16x8 a[4], bb[4];
#pragma unroll
        for (int i = 0; i < 4; ++i) {
            int n = nbase + i * 16 + l15;
            size_t base = ((size_t)(b * 2) * N_ + n) * CI_ + ks * 32 + g16 * 8;
            u16x8 v0 = *(const u16x8*)&of[base];
            u16x8 v1 = *(const u16x8*)&of[base + spstride];
            f16x8 av;
#pragma unroll
            for (int e = 0; e < 8; ++e) {
                float vv = h2f(v0[e]) * wsp[i][0] + h2f(v1[e]) * wsp[i][1];
                av[e] = (_Float16)vv;
            }
            a[i] = av;
        }
#pragma unroll
        for (int j = 0; j < 4; ++j)
            bb[j] = ldh8(&wwf[((size_t)((cbase >> 4) + j) * 4 + ks) * 512 + (size_t)lane * 8]);
#pragma unroll
        for (int i = 0; i < 4; ++i)
#pragma unroll
            for (int j = 0; j < 4; ++j) acc[i][j] = MFMAH(a[i], bb[j], acc[i][j]);
    }
#pragma unroll
    for (int j = 0; j < 4; ++j) {
        int ch = cbase + j * 16 + l15;
        float bias = Wb[ch];
        size_t rowbase = ((size_t)b * C_ + ch) * N_;
#pragma unroll
        for (int i = 0; i < 4; ++i) {
            u16x4 pk;
#pragma unroll
            for (int r = 0; r < 4; ++r) pk[r] = f2h(acc[i][j][r] + bias);
            *reinterpret_cast<u16x4*>(&z[rowbase + nbase + i * 16 + g16 * 4]) = pk;
        }
    }
}

// ---------------- BN stats + finalize ----------------
__global__ __launch_bounds__(256) void k_stats(
    const u16* __restrict__ z, const float* __restrict__ gamma,
    const float* __restrict__ beta, float* __restrict__ bnp) {
    int c = blockIdx.x;
    int tid = threadIdx.x;
    float s = 0.f, q = 0.f;
#pragma unroll
    for (int b = 0; b < B_; ++b) {
        size_t base = ((size_t)b * C_ + c) * N_ + tid * 16;
        u16x8 v0 = *(const u16x8*)&z[base];
        u16x8 v1 = *(const u16x8*)&z[base + 8];
#pragma unroll
        for (int e = 0; e < 8; ++e) {
            float v = h2f(v0[e]);
            s += v;
            q += v * v;
            float u = h2f(v1[e]);
            s += u;
            q += u * u;
        }
    }
#pragma unroll
    for (int off = 1; off <= 32; off <<= 1) {
        s += __shfl_xor(s, off);
        q += __shfl_xor(q, off);
    }
    __shared__ float ss[4], qq[4];
    int w = tid >> 6;
    if ((tid & 63) == 0) {
        ss[w] = s;
        qq[w] = q;
    }
    __syncthreads();
    if (tid == 0) {
        s = ss[0] + ss[1] + ss[2] + ss[3];
        q = qq[0] + qq[1] + qq[2] + qq[3];
        const float inv_n = 1.f / 32768.f;
        float mean = s * inv_n;
        float var = q * inv_n - mean * mean;
        float sc = gamma[c] * rsqrtf(var + 1e-5f);
        bnp[c] = sc;
        bnp[256 + c] = beta[c] - mean * sc;
    }
}

// ---------------- apply BN + residual ----------------
__global__ __launch_bounds__(256) void k_final(
    const float* __restrict__ x, const u16* __restrict__ z,
    const float* __restrict__ bnp, float* __restrict__ out) {
    int i4 = blockIdx.x * 256 + threadIdx.x;
    size_t flat = (size_t)i4 * 4;
    int c = (int)((flat >> 12) & 255);
    float sc = bnp[c], sh = bnp[256 + c];
    float4 xx = *(const float4*)&x[flat];
    u16x4 zz = *(const u16x4*)&z[flat];
    float4 oo;
    oo.x = xx.x + h2f(zz[0]) * sc + sh;
    oo.y = xx.y + h2f(zz[1]) * sc + sh;
    oo.z = xx.z + h2f(zz[2]) * sc + sh;
    oo.w = xx.w + h2f(zz[3]) * sc + sh;
    *(float4*)&out[flat] = oo;
}

extern "C" void kernel_launch(void* const* d_in, const int* in_sizes, int n_in,
                              void* d_out, int out_size, void* d_ws, size_t ws_size,
                              hipStream_t stream) {
    const float* x     = (const float*)d_in[0];
    const float* tw    = (const float*)d_in[1];
    const float* tb    = (const float*)d_in[2];
    const float* pw    = (const float*)d_in[3];
    const float* pb    = (const float*)d_in[4];
    const float* gw    = (const float*)d_in[5];
    const float* gb    = (const float*)d_in[6];
    const float* Ww    = (const float*)d_in[7];
    const float* Wb    = (const float*)d_in[8];
    const float* gamma = (const float*)d_in[9];
    const float* beta  = (const float*)d_in[10];
    float* out = (float*)d_out;

    char* p = (char*)d_ws;
    auto alloc = [&](size_t bytes) {
        char* r = p;
        p += (bytes + 255) & ~(size_t)255;
        return r;
    };
    u16* xbf   = (u16*)alloc((size_t)B_ * N_ * C_ * 2);          // 16.8 MB
    u16* thf   = (u16*)alloc((size_t)B_ * N_ * CI_ * 2);         // 8.4 MB
    u16* ppf   = (u16*)alloc((size_t)B_ * M_ * CI_ * 2);         // 2.1 MB
    u16* gpf   = (u16*)alloc((size_t)B_ * M_ * CI_ * 2);         // 2.1 MB
    float2* ml = (float2*)alloc((size_t)2 * B_ * N_ * 8);        // 512 KB
    u16* of    = (u16*)alloc((size_t)2 * B_ * N_ * CI_ * 2);     // 16.8 MB
    u16* z     = (u16*)alloc((size_t)B_ * C_ * N_ * 2);          // 16.8 MB
    u16* wcf   = (u16*)alloc(384 * 256 * 2);
    u16* wwf   = (u16*)alloc(256 * 128 * 2);
    float* bcat = (float*)alloc(384 * 4);
    float* bnp  = (float*)alloc(512 * 4);

    k_prep<<<514, 256, 0, stream>>>(tw, tb, pw, pb, gw, gb, Ww, wcf, bcat, wwf);
    k_tx<<<2048, 256, 0, stream>>>(x, xbf);
    k_proj<<<768, 256, 0, stream>>>(wcf, bcat, xbf, thf, ppf, gpf);
    k_attn<<<1024, 256, 0, stream>>>(thf, ppf, gpf, of, ml);
    k_wconv<<<512, 256, 0, stream>>>(wwf, Wb, of, ml, z);
    k_stats<<<256, 256, 0, stream>>>(z, gamma, beta, bnp);
    k_final<<<8192, 256, 0, stream>>>(x, z, bnp, out);
}

// Round 21
// 97.694 us; speedup vs baseline: 1.2438x; 1.0607x over previous
//
#include <hip/hip_runtime.h>

#define B_ 8
#define C_ 256
#define CI_ 128
#define N_ 4096
#define M_ 1024

typedef unsigned short u16;
typedef unsigned int u32;
typedef _Float16 f16x8 __attribute__((ext_vector_type(8)));
typedef _Float16 f16x4 __attribute__((ext_vector_type(4)));
typedef float f32x4 __attribute__((ext_vector_type(4)));
typedef u16 u16x4 __attribute__((ext_vector_type(4)));
typedef u16 u16x8 __attribute__((ext_vector_type(8)));

__device__ __forceinline__ u16 f2h(float f) {
    _Float16 h = (_Float16)f;
    u16 u;
    __builtin_memcpy(&u, &h, 2);
    return u;
}
__device__ __forceinline__ float h2f(u16 u) {
    _Float16 h;
    __builtin_memcpy(&h, &u, 2);
    return (float)h;
}
__device__ __forceinline__ f16x8 ldh8(const u16* p) {
    return *reinterpret_cast<const f16x8*>(p);
}
__device__ __forceinline__ f32x4 MFMAH(f16x8 a, f16x8 b, f32x4 c) {
    return __builtin_amdgcn_mfma_f32_16x16x32_f16(a, b, c, 0, 0, 0);
}
__device__ __forceinline__ f32x4 MFMA16(f16x4 a, f16x4 b, f32x4 c) {
    return __builtin_amdgcn_mfma_f32_16x16x16f16(a, b, c, 0, 0, 0);
}
// async global->LDS: lds dst is wave-uniform base, HW adds lane*16B; src per-lane
__device__ __forceinline__ void gld16(const u16* g, u16* l) {
    __builtin_amdgcn_global_load_lds(
        (const __attribute__((address_space(1))) void*)g,
        (__attribute__((address_space(3))) void*)l, 16, 0, 0);
}

// fragment-linear layout: [tile16][ks][lane(64)][8]; value (row-in-16 = lane&15,
// k = ks*32 + (lane>>4)*8 + e). Same layout serves as A-frag (row) or B-frag (col).
// V tile (gpf): K16-frag-linear (see R17), conflict-free mfma16 A-frag reads.

// ---------------- weight prep (fp16) ----------------
__global__ __launch_bounds__(256) void k_prep(
    const float* __restrict__ tw, const float* __restrict__ tb,
    const float* __restrict__ pw, const float* __restrict__ pb,
    const float* __restrict__ gw, const float* __restrict__ gb,
    const float* __restrict__ Ww,
    u16* __restrict__ wcf, float* __restrict__ bcat, u16* __restrict__ wwf) {
    int idx = blockIdx.x * 256 + threadIdx.x;
    if (idx < 384 * 256) {
        int r = idx >> 8, c = idx & 255;
        float v = (r < 128) ? tw[r * 256 + c]
                : (r < 256) ? pw[(r - 128) * 256 + c]
                            : gw[(r - 256) * 256 + c];
        size_t off = (size_t)((r >> 4) * 8 + (c >> 5)) * 512 +
                     (((c >> 3) & 3) * 16 + (r & 15)) * 8 + (c & 7);
        wcf[off] = f2h(v);
    } else if (idx < 384 * 256 + 256 * 128) {
        int k2 = idx - 384 * 256;
        int c = k2 >> 7, k = k2 & 127;
        size_t off = (size_t)((c >> 4) * 4 + (k >> 5)) * 512 +
                     (((k >> 3) & 3) * 16 + (c & 15)) * 8 + (k & 7);
        wwf[off] = f2h(Ww[k2]);
    } else if (idx < 384 * 256 + 256 * 128 + 384) {
        int r = idx - (384 * 256 + 256 * 128);
        bcat[r] = (r < 128) ? tb[r] : (r < 256) ? pb[r - 128] : gb[r - 256];
    }
}

// ---------------- x (B,C,N) fp32 -> fragment-linear fp16 ----------------
__global__ __launch_bounds__(256) void k_tx(const float* __restrict__ x,
                                            u16* __restrict__ xbf) {
    int bid = blockIdx.x;
    int b = bid >> 8, rem = bid & 255, nt = rem >> 2, ct = rem & 3;
    int n0 = nt * 64, c0 = ct * 64;
    __shared__ u16 th_[64][66];
    int j = threadIdx.x & 63, i0 = threadIdx.x >> 6;
    for (int i = i0; i < 64; i += 4)
        th_[i][j] = f2h(x[((size_t)b * C_ + c0 + i) * N_ + n0 + j]);
    __syncthreads();
    int w = threadIdx.x >> 6, lane = threadIdx.x & 63;
    int l15 = lane & 15, g16 = lane >> 4;
    int s = w;
#pragma unroll
    for (int kk = 0; kk < 2; ++kk) {
        u16x8 hv;
#pragma unroll
        for (int e = 0; e < 8; ++e)
            hv[e] = th_[kk * 32 + g16 * 8 + e][s * 16 + l15];
        size_t off = ((size_t)(b * 256 + (n0 >> 4) + s) * 8 + (c0 >> 5) + kk) * 512 +
                     (size_t)lane * 8;
        *(u16x8*)&xbf[off] = hv;
    }
}

// ---------------- projection GEMM (fp16) + fused 2x2 pooling epilogue ----------------
__global__ __launch_bounds__(256) void k_proj(
    const u16* __restrict__ wcf, const float* __restrict__ bcat,
    const u16* __restrict__ xbf,
    u16* __restrict__ thf, u16* __restrict__ ppf, u16* __restrict__ gpf) {
    int bid = blockIdx.x;
    int b = bid / 96, rem = bid % 96, rt = rem >> 5, nt = rem & 31;
    int tid = threadIdx.x;
    int w = tid >> 6, lane = tid & 63;
    int l15 = lane & 15, g16 = lane >> 4;
    int wr = (w >> 1) * 64, wc = (w & 1) * 64;
    int rbase = rt * 128 + wr, nbase = nt * 128 + wc;
    __shared__ u16 tl[128][132];
    f32x4 acc[4][4];
#pragma unroll
    for (int i = 0; i < 4; ++i)
#pragma unroll
        for (int j = 0; j < 4; ++j)
#pragma unroll
            for (int r = 0; r < 4; ++r) acc[i][j][r] = 0.f;
#pragma unroll
    for (int ks = 0; ks < 8; ++ks) {
        f16x8 a[4], bb[4];
#pragma unroll
        for (int i = 0; i < 4; ++i)
            a[i] = ldh8(&wcf[((size_t)((rbase >> 4) + i) * 8 + ks) * 512 + (size_t)lane * 8]);
#pragma unroll
        for (int j = 0; j < 4; ++j)
            bb[j] = ldh8(&xbf[((size_t)(b * 256 + (nbase >> 4) + j) * 8 + ks) * 512 +
                              (size_t)lane * 8]);
#pragma unroll
        for (int i = 0; i < 4; ++i)
#pragma unroll
            for (int j = 0; j < 4; ++j) acc[i][j] = MFMAH(a[i], bb[j], acc[i][j]);
    }
    if (rt == 0) {
#pragma unroll
        for (int i = 0; i < 4; ++i) {
            int lrow = wr + i * 16 + g16 * 4;
#pragma unroll
            for (int j = 0; j < 4; ++j) {
                u16x4 pk;
#pragma unroll
                for (int r = 0; r < 4; ++r)
                    pk[r] = f2h(acc[i][j][r] + bcat[lrow + r]);
                size_t off = ((size_t)(b * 256 + (nbase >> 4) + j) * 4 + (lrow >> 5)) * 512 +
                             (((lrow >> 3) & 3) * 16 + l15) * 8 + (lrow & 7);
                *reinterpret_cast<u16x4*>(&thf[off]) = pk;
            }
        }
    } else {
#pragma unroll
        for (int i = 0; i < 4; ++i) {
            int lrow = wr + i * 16 + g16 * 4;
#pragma unroll
            for (int j = 0; j < 4; ++j) {
                int n_loc = wc + j * 16 + l15;
                u16x4 pk;
#pragma unroll
                for (int r = 0; r < 4; ++r)
                    pk[r] = f2h(acc[i][j][r] + bcat[rt * 128 + lrow + r]);
                *reinterpret_cast<u16x4*>(&tl[n_loc][lrow]) = pk;
            }
        }
        __syncthreads();
        if (rt == 1) {
#pragma unroll
            for (int half = 0; half < 2; ++half) {
                int w2 = (tid >> 4) + half * 16;
                int c8 = tid & 15;
                u16x8 v0 = *(const u16x8*)&tl[2 * w2][c8 * 8];
                u16x8 v1 = *(const u16x8*)&tl[2 * w2 + 1][c8 * 8];
                u16x8 v2 = *(const u16x8*)&tl[64 + 2 * w2][c8 * 8];
                u16x8 v3 = *(const u16x8*)&tl[65 + 2 * w2][c8 * 8];
                u16x8 o;
#pragma unroll
                for (int e = 0; e < 8; ++e) {
                    float mx = fmaxf(fmaxf(h2f(v0[e]), h2f(v1[e])),
                                     fmaxf(h2f(v2[e]), h2f(v3[e])));
                    o[e] = f2h(mx);
                }
                size_t off = ((size_t)(((b * 32 + nt) * 2 + (w2 >> 4)) * 4 + (c8 >> 2)) * 64 +
                              (c8 & 3) * 16 + (w2 & 15)) * 8;
                *(u16x8*)&ppf[off] = o;
            }
        } else {
            // g pooled -> gpf K16-frag-linear (conflict-free mfma16 A-frag reads)
#pragma unroll
            for (int s = 0; s < 2; ++s) {
                int wg = (tid >> 7) + s * 2;
                int ci = tid & 127;
                u16x4 o0, o1;
#pragma unroll
                for (int e = 0; e < 4; ++e) {
                    int w2a = wg * 8 + e;
                    int w2b = wg * 8 + 4 + e;
                    float va = fmaxf(fmaxf(h2f(tl[2 * w2a][ci]), h2f(tl[2 * w2a + 1][ci])),
                                     fmaxf(h2f(tl[64 + 2 * w2a][ci]), h2f(tl[65 + 2 * w2a][ci])));
                    float vb = fmaxf(fmaxf(h2f(tl[2 * w2b][ci]), h2f(tl[2 * w2b + 1][ci])),
                                     fmaxf(h2f(tl[64 + 2 * w2b][ci]), h2f(tl[65 + 2 * w2b][ci])));
                    o0[e] = f2h(va);
                    o1[e] = f2h(vb);
                }
                size_t base = (size_t)(b * 32 + nt) * 4096 +
                              (size_t)(((wg >> 1) * 8) + (ci >> 4)) * 256 + (ci & 15) * 4;
                *(u16x4*)&gpf[base + (((wg * 2) & 3) * 64)] = o0;
                *(u16x4*)&gpf[base + (((wg * 2 + 1) & 3) * 64)] = o1;
            }
        }
    }
}

// ---------------- flash attention (split-m=1: full softmax in-kernel) ----------
// Grid 512 (b x 64 n-tiles). Each block sweeps all 32 m-tiles; writes FINAL
// normalized ytf in fragment-linear order (k_wconv reads it directly).
__global__ __launch_bounds__(256) void k_attn(
    const u16* __restrict__ thf, const u16* __restrict__ ppf,
    const u16* __restrict__ gpf, u16* __restrict__ ytf) {
    int bid = blockIdx.x;
    int b = bid & 7, nt = bid >> 3;  // same-b blocks -> same XCD (L2 locality)
    int tid = threadIdx.x;
    int w = tid >> 6, lane = tid & 63;
    int l15 = lane & 15, g16 = lane >> 4;
    int n = nt * 64 + w * 16 + l15;
    int t16 = nt * 4 + w;
    __shared__ u16 kv[2][8192];  // [buf][0..4096): K-tile, [4096..8192): V-tile

    f16x8 qf[4];
#pragma unroll
    for (int ks = 0; ks < 4; ++ks)
        qf[ks] = ldh8(&thf[((size_t)(b * 256 + t16) * 4 + ks) * 512 + (size_t)lane * 8]);

    f32x4 o[8];
#pragma unroll
    for (int ct = 0; ct < 8; ++ct)
#pragma unroll
        for (int rr = 0; rr < 4; ++rr) o[ct][rr] = 0.f;
    float mrun = -1e30f, lpart = 0.f;

    int soff = w * 512 + lane * 8;  // per-lane src offset (u16)
    auto stage = [&](int bufidx, int itg) {
        const u16* ps = &ppf[(size_t)(b * 32 + itg) * 4096];
        const u16* gs = &gpf[(size_t)(b * 32 + itg) * 4096];
        u16* kb = &kv[bufidx][w * 512];
        gld16(ps + soff, kb);
        gld16(ps + 2048 + soff, kb + 2048);
        gld16(gs + soff, kb + 4096);
        gld16(gs + 2048 + soff, kb + 6144);
    };
    stage(0, 0);
    __syncthreads();  // drains vmcnt -> tile 0 visible
    int cur = 0;

    for (int it = 0; it < 32; ++it) {
        // (A) issue next tile's async loads (land by end-of-iter barrier)
        if (it < 31) stage(cur ^ 1, it + 1);
        // (B) QK^T from kv[cur]
        f32x4 s0 = {0.f, 0.f, 0.f, 0.f}, s1 = {0.f, 0.f, 0.f, 0.f};
        __builtin_amdgcn_s_setprio(1);
#pragma unroll
        for (int ks = 0; ks < 4; ++ks) {
            f16x8 pa0 = ldh8(&kv[cur][ks * 512 + lane * 8]);
            f16x8 pa1 = ldh8(&kv[cur][(4 + ks) * 512 + lane * 8]);
            s0 = MFMAH(pa0, qf[ks], s0);
            s1 = MFMAH(pa1, qf[ks], s1);
        }
        __builtin_amdgcn_s_setprio(0);
        // lane-local max; ballot-gated lazy rescale (P bounded by e^8, fp16-safe)
        float pm8 = s0[0];
#pragma unroll
        for (int rr = 1; rr < 4; ++rr) pm8 = fmaxf(pm8, s0[rr]);
#pragma unroll
        for (int rr = 0; rr < 4; ++rr) pm8 = fmaxf(pm8, s1[rr]);
        if (__any(pm8 > mrun + 8.0f)) {
            float pm = fmaxf(pm8, __shfl_xor(pm8, 16));
            pm = fmaxf(pm, __shfl_xor(pm, 32));
            float mnew = fmaxf(mrun, pm);
            float sc = __expf(mrun - mnew);
#pragma unroll
            for (int ct = 0; ct < 8; ++ct)
#pragma unroll
                for (int rr = 0; rr < 4; ++rr) o[ct][rr] *= sc;
            lpart *= sc;
            mrun = mnew;
        }
        // P stays in registers: pack directly into the two 16x16x16 B-frags.
        f16x4 pb0, pb1;
#pragma unroll
        for (int rr = 0; rr < 4; ++rr) {
            float p0 = __expf(s0[rr] - mrun);
            float p1 = __expf(s1[rr] - mrun);
            lpart += p0 + p1;
            pb0[rr] = (_Float16)p0;
            pb1[rr] = (_Float16)p1;
        }
        // (C) PV from kv[cur] V-tile (K16-frag-linear): conflict-free 8B reads
        __builtin_amdgcn_s_setprio(1);
#pragma unroll
        for (int ct = 0; ct < 8; ++ct) {
            f16x4 g0 = *reinterpret_cast<const f16x4*>(&kv[cur][4096 + ct * 256 + lane * 4]);
            f16x4 g1 = *reinterpret_cast<const f16x4*>(&kv[cur][6144 + ct * 256 + lane * 4]);
            o[ct] = MFMA16(g0, pb0, o[ct]);
            o[ct] = MFMA16(g1, pb1, o[ct]);
        }
        __builtin_amdgcn_s_setprio(0);
        __syncthreads();  // drains vmcnt (next tile staged) + all kv[cur] reads done
        cur ^= 1;
    }
    // full column l-sum (exact softmax, no combine pass needed)
    float lcol = lpart + __shfl_xor(lpart, 16);
    lcol += __shfl_xor(lcol, 32);
    float linv = 1.f / lcol;
    // write final ytf in fragment-linear order (k_wconv A-frag reads directly)
    size_t obase = ((size_t)b * N_ + n) * CI_;
#pragma unroll
    for (int ct = 0; ct < 8; ++ct) {
        u16x4 pk;
#pragma unroll
        for (int rr = 0; rr < 4; ++rr) pk[rr] = f2h(o[ct][rr] * linv);
        *reinterpret_cast<u16x4*>(&ytf[obase + ct * 16 + g16 * 4]) = pk;
    }
}

// ---------------- W conv GEMM (pure fp16 GEMM, direct ytf A-frags) ----------------
__global__ __launch_bounds__(256) void k_wconv(
    const u16* __restrict__ wwf, const float* __restrict__ Wb,
    const u16* __restrict__ ytf, u16* __restrict__ z) {
    int bid = blockIdx.x;
    int b = bid >> 6, rem = bid & 63, ct2 = rem >> 5, nt = rem & 31;
    int w = threadIdx.x >> 6, lane = threadIdx.x & 63;
    int l15 = lane & 15, g16 = lane >> 4;
    int nbase = nt * 128 + (w >> 1) * 64;
    int cbase = ct2 * 128 + (w & 1) * 64;
    f32x4 acc[4][4];
#pragma unroll
    for (int i = 0; i < 4; ++i)
#pragma unroll
        for (int j = 0; j < 4; ++j)
#pragma unroll
            for (int r = 0; r < 4; ++r) acc[i][j][r] = 0.f;
#pragma unroll
    for (int ks = 0; ks < 4; ++ks) {
        f16x8 a[4], bb[4];
#pragma unroll
        for (int i = 0; i < 4; ++i) {
            int n = nbase + i * 16 + l15;
            a[i] = ldh8(&ytf[((size_t)b * N_ + n) * CI_ + ks * 32 + g16 * 8]);
        }
#pragma unroll
        for (int j = 0; j < 4; ++j)
            bb[j] = ldh8(&wwf[((size_t)((cbase >> 4) + j) * 4 + ks) * 512 + (size_t)lane * 8]);
#pragma unroll
        for (int i = 0; i < 4; ++i)
#pragma unroll
            for (int j = 0; j < 4; ++j) acc[i][j] = MFMAH(a[i], bb[j], acc[i][j]);
    }
#pragma unroll
    for (int j = 0; j < 4; ++j) {
        int ch = cbase + j * 16 + l15;
        float bias = Wb[ch];
        size_t rowbase = ((size_t)b * C_ + ch) * N_;
#pragma unroll
        for (int i = 0; i < 4; ++i) {
            u16x4 pk;
#pragma unroll
            for (int r = 0; r < 4; ++r) pk[r] = f2h(acc[i][j][r] + bias);
            *reinterpret_cast<u16x4*>(&z[rowbase + nbase + i * 16 + g16 * 4]) = pk;
        }
    }
}

// ---------------- BN stats + finalize ----------------
__global__ __launch_bounds__(256) void k_stats(
    const u16* __restrict__ z, const float* __restrict__ gamma,
    const float* __restrict__ beta, float* __restrict__ bnp) {
    int c = blockIdx.x;
    int tid = threadIdx.x;
    float s = 0.f, q = 0.f;
#pragma unroll
    for (int b = 0; b < B_; ++b) {
        size_t base = ((size_t)b * C_ + c) * N_ + tid * 16;
        u16x8 v0 = *(const u16x8*)&z[base];
        u16x8 v1 = *(const u16x8*)&z[base + 8];
#pragma unroll
        for (int e = 0; e < 8; ++e) {
            float v = h2f(v0[e]);
            s += v;
            q += v * v;
            float u = h2f(v1[e]);
            s += u;
            q += u * u;
        }
    }
#pragma unroll
    for (int off = 1; off <= 32; off <<= 1) {
        s += __shfl_xor(s, off);
        q += __shfl_xor(q, off);
    }
    __shared__ float ss[4], qq[4];
    int w = tid >> 6;
    if ((tid & 63) == 0) {
        ss[w] = s;
        qq[w] = q;
    }
    __syncthreads();
    if (tid == 0) {
        s = ss[0] + ss[1] + ss[2] + ss[3];
        q = qq[0] + qq[1] + qq[2] + qq[3];
        const float inv_n = 1.f / 32768.f;
        float mean = s * inv_n;
        float var = q * inv_n - mean * mean;
        float sc = gamma[c] * rsqrtf(var + 1e-5f);
        bnp[c] = sc;
        bnp[256 + c] = beta[c] - mean * sc;
    }
}

// ---------------- apply BN + residual ----------------
__global__ __launch_bounds__(256) void k_final(
    const float* __restrict__ x, const u16* __restrict__ z,
    const float* __restrict__ bnp, float* __restrict__ out) {
    int i4 = blockIdx.x * 256 + threadIdx.x;
    size_t flat = (size_t)i4 * 4;
    int c = (int)((flat >> 12) & 255);
    float sc = bnp[c], sh = bnp[256 + c];
    float4 xx = *(const float4*)&x[flat];
    u16x4 zz = *(const u16x4*)&z[flat];
    float4 oo;
    oo.x = xx.x + h2f(zz[0]) * sc + sh;
    oo.y = xx.y + h2f(zz[1]) * sc + sh;
    oo.z = xx.z + h2f(zz[2]) * sc + sh;
    oo.w = xx.w + h2f(zz[3]) * sc + sh;
    *(float4*)&out[flat] = oo;
}

extern "C" void kernel_launch(void* const* d_in, const int* in_sizes, int n_in,
                              void* d_out, int out_size, void* d_ws, size_t ws_size,
                              hipStream_t stream) {
    const float* x     = (const float*)d_in[0];
    const float* tw    = (const float*)d_in[1];
    const float* tb    = (const float*)d_in[2];
    const float* pw    = (const float*)d_in[3];
    const float* pb    = (const float*)d_in[4];
    const float* gw    = (const float*)d_in[5];
    const float* gb    = (const float*)d_in[6];
    const float* Ww    = (const float*)d_in[7];
    const float* Wb    = (const float*)d_in[8];
    const float* gamma = (const float*)d_in[9];
    const float* beta  = (const float*)d_in[10];
    float* out = (float*)d_out;

    char* p = (char*)d_ws;
    auto alloc = [&](size_t bytes) {
        char* r = p;
        p += (bytes + 255) & ~(size_t)255;
        return r;
    };
    u16* xbf   = (u16*)alloc((size_t)B_ * N_ * C_ * 2);          // 16.8 MB
    u16* thf   = (u16*)alloc((size_t)B_ * N_ * CI_ * 2);         // 8.4 MB
    u16* ppf   = (u16*)alloc((size_t)B_ * M_ * CI_ * 2);         // 2.1 MB
    u16* gpf   = (u16*)alloc((size_t)B_ * M_ * CI_ * 2);         // 2.1 MB
    u16* ytf   = (u16*)alloc((size_t)B_ * N_ * CI_ * 2);         // 8.4 MB
    u16* z     = (u16*)alloc((size_t)B_ * C_ * N_ * 2);          // 16.8 MB
    u16* wcf   = (u16*)alloc(384 * 256 * 2);
    u16* wwf   = (u16*)alloc(256 * 128 * 2);
    float* bcat = (float*)alloc(384 * 4);
    float* bnp  = (float*)alloc(512 * 4);

    k_prep<<<514, 256, 0, stream>>>(tw, tb, pw, pb, gw, gb, Ww, wcf, bcat, wwf);
    k_tx<<<2048, 256, 0, stream>>>(x, xbf);
    k_proj<<<768, 256, 0, stream>>>(wcf, bcat, xbf, thf, ppf, gpf);
    k_attn<<<512, 256, 0, stream>>>(thf, ppf, gpf, ytf);
    k_wconv<<<512, 256, 0, stream>>>(wwf, Wb, ytf, z);
    k_stats<<<256, 256, 0, stream>>>(z, gamma, beta, bnp);
    k_final<<<8192, 256, 0, stream>>>(x, z, bnp, out);
}